// Round 1
// baseline (143.897 us; speedup 1.0000x reference)
//
#include <hip/hip_runtime.h>

#define BB 4
#define CC 128
#define HH 56
#define WW 56
#define NK2 9
#define NO 18
#define WSZ 4

__global__ __launch_bounds__(256) void deform_fused(
    const float* __restrict__ x,         // [B][C][H][W]
    const float* __restrict__ offset_w,  // [18][C][3][3]
    const float* __restrict__ offset_b,  // [18]
    const float* __restrict__ weight,    // [C][4][4]
    float* __restrict__ out)             // [B][C][H][W]
{
    const int bh = blockIdx.x;          // 0..223
    const int b  = bh / HH;
    const int h  = bh - b * HH;
    const int t  = threadIdx.x;
    const int lane = t & 63;
    // wave id: uniform within wave; force scalar so weight addrs become s_loads
    const int wv = __builtin_amdgcn_readfirstlane(t >> 6);   // 0..3

    __shared__ float    s_red[4][NO][64];   // 18 KiB  partial conv sums
    __shared__ float    s_off[NO][64];      // 4.5 KiB final offsets for this row
    __shared__ float    s_w[CC][16];        // 8 KiB   weight
    __shared__ float    s_coef[NK2][64][4]; // 9 KiB   bilinear coefs
    __shared__ unsigned s_idx[NK2][64];     // 2.25KiB packed 4x4-bit indices

    // stage weight into LDS
    for (int i = t; i < CC * 16; i += 256) ((float*)s_w)[i] = weight[i];

    // ---------------- phase 1: offset conv (18 outputs, this row) ----------
    float acc[NO];
    #pragma unroll
    for (int o = 0; o < NO; ++o) acc[o] = 0.f;

    const int c0 = wv * 32;   // this wave's channel slice
    if (lane < WW) {
        const float* xb = x + (long)b * CC * HH * WW;
        for (int ci = 0; ci < 32; ++ci) {
            const int c = c0 + ci;
            const float* xc = xb + c * HH * WW;
            #pragma unroll
            for (int ky = 0; ky < 3; ++ky) {
                const int hy = h + ky - 1;
                float x0 = 0.f, x1 = 0.f, x2 = 0.f;
                if (hy >= 0 && hy < HH) {
                    const float* r = xc + hy * WW;
                    x1 = r[lane];
                    x0 = (lane > 0)      ? r[lane - 1] : 0.f;
                    x2 = (lane < WW - 1) ? r[lane + 1] : 0.f;
                }
                const float* wp = offset_w + c * 9 + ky * 3;  // uniform addr
                #pragma unroll
                for (int o = 0; o < NO; ++o) {
                    const float* wo = wp + o * (CC * 9);
                    acc[o] += x0 * wo[0] + x1 * wo[1] + x2 * wo[2];
                }
            }
        }
    }
    #pragma unroll
    for (int o = 0; o < NO; ++o) s_red[wv][o][lane] = acc[o];
    __syncthreads();

    // cross-wave reduce + bias
    for (int s = t; s < NO * 64; s += 256) {
        const int o = s >> 6, l = s & 63;
        s_off[o][l] = s_red[0][o][l] + s_red[1][o][l] + s_red[2][o][l] +
                      s_red[3][o][l] + offset_b[o];
    }
    __syncthreads();

    // ---------------- phase 1b: bilinear coefs/indices per (k2, w) ---------
    for (int s = t; s < NK2 * 64; s += 256) {
        const int k2 = s >> 6, wq = s & 63;
        const float dy = s_off[2 * k2][wq];
        const float dx = s_off[2 * k2 + 1][wq];
        const float yc = dy + 0.5f + (float)(k2 / 3);
        const float xc = dx + 0.5f + (float)(k2 % 3);
        const float y0 = floorf(yc), x0f = floorf(xc);
        const float fy = yc - y0, fx = xc - x0f;
        const int yi = (int)y0, xi = (int)x0f;
        float cf[4]; int id[4];
        #pragma unroll
        for (int q = 0; q < 4; ++q) {
            const int oy = q >> 1, ox = q & 1;
            const int yy = yi + oy, xx = xi + ox;
            float c2 = (oy ? fy : 1.f - fy) * (ox ? fx : 1.f - fx);
            const bool valid = (yy >= 0) && (yy < WSZ) && (xx >= 0) && (xx < WSZ);
            cf[q] = valid ? c2 : 0.f;
            const int yyc = yy < 0 ? 0 : (yy > 3 ? 3 : yy);
            const int xxc = xx < 0 ? 0 : (xx > 3 ? 3 : xx);
            id[q] = yyc * 4 + xxc;
        }
        s_coef[k2][wq][0] = cf[0];
        s_coef[k2][wq][1] = cf[1];
        s_coef[k2][wq][2] = cf[2];
        s_coef[k2][wq][3] = cf[3];
        s_idx[k2][wq] = (unsigned)(id[0] | (id[1] << 4) | (id[2] << 8) | (id[3] << 12));
    }
    __syncthreads();

    // ---------------- phase 2: sample weights, multiply patches ------------
    if (lane < WW) {
        const int w = lane;
        for (int cb = 0; cb < 32; cb += 4) {
            float res[4] = {0.f, 0.f, 0.f, 0.f};
            float xv[4][9];
            #pragma unroll
            for (int u = 0; u < 4; ++u) {
                const int c = c0 + cb + u;
                const float* xc = x + ((long)b * CC + c) * HH * WW;
                #pragma unroll
                for (int ky = 0; ky < 3; ++ky) {
                    const int hy = h + ky - 1;
                    #pragma unroll
                    for (int kx = 0; kx < 3; ++kx) {
                        const int wx = w + kx - 1;
                        float v = 0.f;
                        if (hy >= 0 && hy < HH && wx >= 0 && wx < WW)
                            v = xc[hy * WW + wx];
                        xv[u][ky * 3 + kx] = v;
                    }
                }
            }
            #pragma unroll
            for (int k2 = 0; k2 < NK2; ++k2) {
                const float4 cf = *(const float4*)&s_coef[k2][w][0];
                const unsigned p = s_idx[k2][w];
                const int i0 = p & 15, i1 = (p >> 4) & 15,
                          i2 = (p >> 8) & 15, i3 = (p >> 12) & 15;
                #pragma unroll
                for (int u = 0; u < 4; ++u) {
                    const int c = c0 + cb + u;
                    const float samp = cf.x * s_w[c][i0] + cf.y * s_w[c][i1] +
                                       cf.z * s_w[c][i2] + cf.w * s_w[c][i3];
                    res[u] += samp * xv[u][k2];
                }
            }
            #pragma unroll
            for (int u = 0; u < 4; ++u) {
                const int c = c0 + cb + u;
                out[(((long)b * CC + c) * HH + h) * WW + w] = res[u];
            }
        }
    }
}

extern "C" void kernel_launch(void* const* d_in, const int* in_sizes, int n_in,
                              void* d_out, int out_size, void* d_ws, size_t ws_size,
                              hipStream_t stream) {
    const float* x        = (const float*)d_in[0];
    const float* offset_w = (const float*)d_in[1];
    const float* offset_b = (const float*)d_in[2];
    const float* weight   = (const float*)d_in[3];
    float* out = (float*)d_out;
    deform_fused<<<BB * HH, 256, 0, stream>>>(x, offset_w, offset_b, weight, out);
}

// Round 2
// 125.145 us; speedup vs baseline: 1.1498x; 1.1498x over previous
//
#include <hip/hip_runtime.h>

#define BB 4
#define CC 128
#define HH 56
#define WW 56
#define NK2 9
#define NO 18
#define WSZ 4

// 1024 threads = 16 waves = 4 waves/SIMD (latency hiding), one block per (b,h).
__global__ __launch_bounds__(1024) void deform_fused(
    const float* __restrict__ x,         // [B][C][H][W]
    const float* __restrict__ offset_w,  // [18][C][3][3]
    const float* __restrict__ offset_b,  // [18]
    const float* __restrict__ weight,    // [C][4][4]
    float* __restrict__ out)             // [B][C][H][W]
{
    const int bh = blockIdx.x;          // 0..223
    const int b  = bh / HH;
    const int h  = bh - b * HH;
    const int t  = threadIdx.x;
    const int lane = t & 63;
    const int wv = __builtin_amdgcn_readfirstlane(t >> 6);   // 0..15

    __shared__ float    s_red[8][NO][64];   // 36 KiB  partial conv sums (pairwise)
    __shared__ float    s_off[NO][64];      // 4.5 KiB final offsets for this row
    __shared__ float    s_w[CC][16];        // 8 KiB   weight
    __shared__ float    s_coef[NK2][64][4]; // 9 KiB   bilinear coefs
    __shared__ unsigned s_idx[NK2][64];     // 2.25KiB packed 4x4-bit indices

    // stage weight into LDS
    for (int i = t; i < CC * 16; i += 1024) ((float*)s_w)[i] = weight[i];

    // ---------------- phase 1: offset conv (18 outputs, this row) ----------
    float acc[NO];
    #pragma unroll
    for (int o = 0; o < NO; ++o) acc[o] = 0.f;

    const int c0 = wv * 8;   // this wave's 8-channel slice
    if (lane < WW) {
        const float* xb = x + (long)b * CC * HH * WW;
        #pragma unroll
        for (int ci = 0; ci < 8; ++ci) {
            const int c = c0 + ci;
            const float* xc = xb + c * HH * WW;
            #pragma unroll
            for (int ky = 0; ky < 3; ++ky) {
                const int hy = h + ky - 1;
                float x0 = 0.f, x1 = 0.f, x2 = 0.f;
                if (hy >= 0 && hy < HH) {
                    const float* r = xc + hy * WW;
                    x1 = r[lane];
                    x0 = (lane > 0)      ? r[lane - 1] : 0.f;
                    x2 = (lane < WW - 1) ? r[lane + 1] : 0.f;
                }
                const float* wp = offset_w + c * 9 + ky * 3;  // wave-uniform addr
                #pragma unroll
                for (int o = 0; o < NO; ++o) {
                    const float* wo = wp + o * (CC * 9);
                    acc[o] += x0 * wo[0] + x1 * wo[1] + x2 * wo[2];
                }
            }
        }
    }
    // pairwise cross-wave reduce: 16 partials -> 8 slots
    if (wv < 8) {
        #pragma unroll
        for (int o = 0; o < NO; ++o) s_red[wv][o][lane] = acc[o];
    }
    __syncthreads();
    if (wv >= 8) {
        #pragma unroll
        for (int o = 0; o < NO; ++o) s_red[wv - 8][o][lane] += acc[o];
    }
    __syncthreads();

    // final reduce of 8 + bias
    for (int s = t; s < NO * 64; s += 1024) {
        const int o = s >> 6, l = s & 63;
        float v = offset_b[o];
        #pragma unroll
        for (int r = 0; r < 8; ++r) v += s_red[r][o][l];
        s_off[o][l] = v;
    }
    __syncthreads();

    // ---------------- phase 1b: bilinear coefs/indices per (k2, w) ---------
    if (t < NK2 * 64) {
        const int k2 = t >> 6, wq = t & 63;
        const float dy = s_off[2 * k2][wq];
        const float dx = s_off[2 * k2 + 1][wq];
        const float yc = dy + 0.5f + (float)(k2 / 3);
        const float xc = dx + 0.5f + (float)(k2 % 3);
        const float y0 = floorf(yc), x0f = floorf(xc);
        const float fy = yc - y0, fx = xc - x0f;
        const int yi = (int)y0, xi = (int)x0f;
        float cf[4]; int id[4];
        #pragma unroll
        for (int q = 0; q < 4; ++q) {
            const int oy = q >> 1, ox = q & 1;
            const int yy = yi + oy, xx = xi + ox;
            float c2 = (oy ? fy : 1.f - fy) * (ox ? fx : 1.f - fx);
            const bool valid = (yy >= 0) && (yy < WSZ) && (xx >= 0) && (xx < WSZ);
            cf[q] = valid ? c2 : 0.f;
            const int yyc = yy < 0 ? 0 : (yy > 3 ? 3 : yy);
            const int xxc = xx < 0 ? 0 : (xx > 3 ? 3 : xx);
            id[q] = yyc * 4 + xxc;
        }
        s_coef[k2][wq][0] = cf[0];
        s_coef[k2][wq][1] = cf[1];
        s_coef[k2][wq][2] = cf[2];
        s_coef[k2][wq][3] = cf[3];
        s_idx[k2][wq] = (unsigned)(id[0] | (id[1] << 4) | (id[2] << 8) | (id[3] << 12));
    }
    __syncthreads();

    // ---------------- phase 2: sample weights, multiply patches ------------
    if (lane < WW) {
        const int w = lane;
        #pragma unroll
        for (int cb = 0; cb < 8; cb += 4) {
            float res[4] = {0.f, 0.f, 0.f, 0.f};
            float xv[4][9];
            #pragma unroll
            for (int u = 0; u < 4; ++u) {
                const int c = c0 + cb + u;
                const float* xc = x + ((long)b * CC + c) * HH * WW;
                #pragma unroll
                for (int ky = 0; ky < 3; ++ky) {
                    const int hy = h + ky - 1;
                    #pragma unroll
                    for (int kx = 0; kx < 3; ++kx) {
                        const int wx = w + kx - 1;
                        float v = 0.f;
                        if (hy >= 0 && hy < HH && wx >= 0 && wx < WW)
                            v = xc[hy * WW + wx];
                        xv[u][ky * 3 + kx] = v;
                    }
                }
            }
            #pragma unroll
            for (int k2 = 0; k2 < NK2; ++k2) {
                const float4 cf = *(const float4*)&s_coef[k2][w][0];
                const unsigned p = s_idx[k2][w];
                const int i0 = p & 15, i1 = (p >> 4) & 15,
                          i2 = (p >> 8) & 15, i3 = (p >> 12) & 15;
                #pragma unroll
                for (int u = 0; u < 4; ++u) {
                    const int c = c0 + cb + u;
                    const float samp = cf.x * s_w[c][i0] + cf.y * s_w[c][i1] +
                                       cf.z * s_w[c][i2] + cf.w * s_w[c][i3];
                    res[u] += samp * xv[u][k2];
                }
            }
            #pragma unroll
            for (int u = 0; u < 4; ++u) {
                const int c = c0 + cb + u;
                out[(((long)b * CC + c) * HH + h) * WW + w] = res[u];
            }
        }
    }
}

extern "C" void kernel_launch(void* const* d_in, const int* in_sizes, int n_in,
                              void* d_out, int out_size, void* d_ws, size_t ws_size,
                              hipStream_t stream) {
    const float* x        = (const float*)d_in[0];
    const float* offset_w = (const float*)d_in[1];
    const float* offset_b = (const float*)d_in[2];
    const float* weight   = (const float*)d_in[3];
    float* out = (float*)d_out;
    deform_fused<<<BB * HH, 1024, 0, stream>>>(x, offset_w, offset_b, weight, out);
}

// Round 3
// 110.523 us; speedup vs baseline: 1.3020x; 1.1323x over previous
//
#include <hip/hip_runtime.h>

#define BB 4
#define CC 128
#define HH 56
#define WW 56
#define NK2 9
#define NO 18
#define WSZ 4
#define CG 8      // channel groups
#define CPG 16    // channels per group
#define W64 64    // padded row width

// ws layout (bytes):
//   wsA : float [BB*HH][CG][NO][W64]   = 224*8*18*64*4 = 8,257,536
//   wsC : float4 [BB][NK2][HH][W64]    = 129024*16     = 2,064,384
//   wsI : uint   [BB][NK2][HH][W64]    = 129024*4      =   516,096
#define WSA_FLOATS (224L * CG * NO * W64)
#define WSC_ENTRIES (4L * NK2 * HH * W64)

// ---------------- Kernel A: 18-ch offset conv, 16-channel partials ----------
__global__ __launch_bounds__(256) void conv_partial(
    const float* __restrict__ x,         // [B][C][H][W]
    const float* __restrict__ offset_w,  // [18][C][3][3]
    float* __restrict__ wsA)
{
    const int blk = blockIdx.x;          // 0..1791 = bh*8 + cg
    const int bh  = blk >> 3;
    const int cg  = blk & 7;
    const int b   = bh / HH;
    const int h   = bh - b * HH;
    const int t   = threadIdx.x;
    const int lane = t & 63;
    const int wv  = __builtin_amdgcn_readfirstlane(t >> 6);  // 0..3

    __shared__ float s_red[4][NO][W64];  // 18 KiB

    float acc[NO];
    #pragma unroll
    for (int o = 0; o < NO; ++o) acc[o] = 0.f;

    const int c0 = cg * CPG + wv * 4;
    if (lane < WW) {
        const float* xb = x + (long)b * CC * HH * WW;
        #pragma unroll
        for (int ci = 0; ci < 4; ++ci) {
            const int c = c0 + ci;
            const float* xc = xb + c * HH * WW;
            #pragma unroll
            for (int ky = 0; ky < 3; ++ky) {
                const int hy = h + ky - 1;
                float x0 = 0.f, x1 = 0.f, x2 = 0.f;
                if (hy >= 0 && hy < HH) {
                    const float* r = xc + hy * WW;
                    x1 = r[lane];
                    x0 = (lane > 0)      ? r[lane - 1] : 0.f;
                    x2 = (lane < WW - 1) ? r[lane + 1] : 0.f;
                }
                const float* wp = offset_w + c * 9 + ky * 3;  // wave-uniform
                #pragma unroll
                for (int o = 0; o < NO; ++o) {
                    const float* wo = wp + o * (CC * 9);
                    acc[o] += x0 * wo[0] + x1 * wo[1] + x2 * wo[2];
                }
            }
        }
    }
    #pragma unroll
    for (int o = 0; o < NO; ++o) s_red[wv][o][lane] = acc[o];
    __syncthreads();

    const float* sr = (const float*)s_red;
    float* dst = wsA + (long)blk * (NO * W64);
    for (int s = t; s < NO * W64; s += 256) {
        dst[s] = sr[s] + sr[NO * W64 + s] + sr[2 * NO * W64 + s] + sr[3 * NO * W64 + s];
    }
}

// ---------------- Kernel A2: reduce partials -> bilinear coefs --------------
__global__ __launch_bounds__(64) void coef_kernel(
    const float* __restrict__ wsA,
    const float* __restrict__ offset_b,
    float4* __restrict__ wsC,
    unsigned* __restrict__ wsI)
{
    const int blk = blockIdx.x;          // 0..2015 = bh*9 + k2
    const int k2  = blk % NK2;
    const int bh  = blk / NK2;
    const int b   = bh / HH;
    const int h   = bh - b * HH;
    const int w   = threadIdx.x;         // 0..63 (pad lanes write pad slots)

    const float* base = wsA + (long)bh * (CG * NO * W64);
    float dy = offset_b[2 * k2];
    float dx = offset_b[2 * k2 + 1];
    #pragma unroll
    for (int g = 0; g < CG; ++g) {
        dy += base[g * (NO * W64) + (2 * k2) * W64 + w];
        dx += base[g * (NO * W64) + (2 * k2 + 1) * W64 + w];
    }

    const float yc = dy + 0.5f + (float)(k2 / 3);
    const float xc = dx + 0.5f + (float)(k2 % 3);
    const float y0 = floorf(yc), x0f = floorf(xc);
    const float fy = yc - y0, fx = xc - x0f;
    const int yi = (int)y0, xi = (int)x0f;
    float cf[4]; int id[4];
    #pragma unroll
    for (int q = 0; q < 4; ++q) {
        const int oy = q >> 1, ox = q & 1;
        const int yy = yi + oy, xx = xi + ox;
        float c2 = (oy ? fy : 1.f - fy) * (ox ? fx : 1.f - fx);
        const bool valid = (yy >= 0) && (yy < WSZ) && (xx >= 0) && (xx < WSZ);
        cf[q] = valid ? c2 : 0.f;
        const int yyc = yy < 0 ? 0 : (yy > 3 ? 3 : yy);
        const int xxc = xx < 0 ? 0 : (xx > 3 ? 3 : xx);
        id[q] = yyc * 4 + xxc;
    }
    const long oidx = ((long)(b * NK2 + k2) * HH + h) * W64 + w;
    wsC[oidx] = make_float4(cf[0], cf[1], cf[2], cf[3]);
    wsI[oidx] = (unsigned)(id[0] | (id[1] << 4) | (id[2] << 8) | (id[3] << 12));
}

// ---------------- Kernel B: weight sampling + patch multiply ----------------
__global__ __launch_bounds__(256) void sample_kernel(
    const float* __restrict__ x,        // [B][C][H][W]
    const float* __restrict__ weight,   // [C][16]
    const float4* __restrict__ wsC,
    const unsigned* __restrict__ wsI,
    float* __restrict__ out)            // [B][C][H][W]
{
    const int blk = blockIdx.x;          // bh*8 + cg
    const int bh  = blk >> 3;
    const int cg  = blk & 7;
    const int b   = bh / HH;
    const int h   = bh - b * HH;
    const int t   = threadIdx.x;
    const int lane = t & 63;
    const int wv  = __builtin_amdgcn_readfirstlane(t >> 6);  // 0..3

    __shared__ float s_w[CPG][16];       // 1 KiB: this block's 16 channels
    if (t < CPG * 16) ((float*)s_w)[t] = weight[cg * CPG * 16 + t];
    __syncthreads();

    if (lane >= WW) return;
    const int w = lane;

    // preload all 9 coef/idx entries for this pixel (coalesced 16B/lane)
    float4 cf[NK2]; unsigned pk[NK2];
    const long cidx0 = ((long)b * NK2 * HH + h) * W64 + w;
    #pragma unroll
    for (int k2 = 0; k2 < NK2; ++k2) {
        cf[k2] = wsC[cidx0 + (long)k2 * HH * W64];
        pk[k2] = wsI[cidx0 + (long)k2 * HH * W64];
    }

    const int cl0 = wv * 4;              // local channel base within block
    #pragma unroll
    for (int u = 0; u < 4; ++u) {
        const int cl = cl0 + u;
        const int c  = cg * CPG + cl;
        const float* xc = x + ((long)b * CC + c) * HH * WW;
        float xv[9];
        #pragma unroll
        for (int ky = 0; ky < 3; ++ky) {
            const int hy = h + ky - 1;
            #pragma unroll
            for (int kx = 0; kx < 3; ++kx) {
                const int wx = w + kx - 1;
                float v = 0.f;
                if (hy >= 0 && hy < HH && wx >= 0 && wx < WW)
                    v = xc[hy * WW + wx];
                xv[ky * 3 + kx] = v;
            }
        }
        float res = 0.f;
        #pragma unroll
        for (int k2 = 0; k2 < NK2; ++k2) {
            const unsigned p = pk[k2];
            const float samp = cf[k2].x * s_w[cl][p & 15]
                             + cf[k2].y * s_w[cl][(p >> 4) & 15]
                             + cf[k2].z * s_w[cl][(p >> 8) & 15]
                             + cf[k2].w * s_w[cl][(p >> 12) & 15];
            res += samp * xv[k2];
        }
        out[(((long)b * CC + c) * HH + h) * WW + w] = res;
    }
}

extern "C" void kernel_launch(void* const* d_in, const int* in_sizes, int n_in,
                              void* d_out, int out_size, void* d_ws, size_t ws_size,
                              hipStream_t stream) {
    const float* x        = (const float*)d_in[0];
    const float* offset_w = (const float*)d_in[1];
    const float* offset_b = (const float*)d_in[2];
    const float* weight   = (const float*)d_in[3];
    float* out = (float*)d_out;

    float*    wsA = (float*)d_ws;
    float4*   wsC = (float4*)((char*)d_ws + WSA_FLOATS * 4);
    unsigned* wsI = (unsigned*)((char*)d_ws + WSA_FLOATS * 4 + WSC_ENTRIES * 16);

    conv_partial <<<224 * CG, 256, 0, stream>>>(x, offset_w, wsA);
    coef_kernel  <<<224 * NK2, 64, 0, stream>>>(wsA, offset_b, wsC, wsI);
    sample_kernel<<<224 * CG, 256, 0, stream>>>(x, weight, wsC, wsI, out);
}